// Round 1
// baseline (621.720 us; speedup 1.0000x reference)
//
#include <hip/hip_runtime.h>
#include <hip/hip_bf16.h>

// Problem constants (from reference): N=100000 nodes, E=1.6M edges,
// IN_C=256, HID_C=128, OUT_C=256. All float32; src/dst int32.

// ---------------------------------------------------------------------------
// Kernel 1: degree counts via atomics.
__global__ __launch_bounds__(256) void deg_kernel(
    const int* __restrict__ src, const int* __restrict__ dst,
    int* __restrict__ outdeg, int* __restrict__ indeg, int nE)
{
    int i = blockIdx.x * 256 + threadIdx.x;
    int stride = gridDim.x * 256;
    for (; i < nE; i += stride) {
        atomicAdd(&outdeg[src[i]], 1);
        atomicAdd(&indeg[dst[i]], 1);
    }
}

// ---------------------------------------------------------------------------
// Kernel 2: tiled f32 GEMM, 64 rows x 128 cols per block, 256 threads,
// 8x4 register tile per thread, K staged in 64-wide chunks.
//
// IN_MODE: 0 = A as-is
//          1 = A row scaled by rsqrt(max(deg,1))
//          2 = relu(A*rsqrt(max(deg,1)) + bias_in[k])   (the GraphConv dst side)
// B_NK:    0 = B is [K][nColsTotal] (W_conv layout)
//          1 = B is [nColsTotal][K] (torch Linear weight layout, C = A @ B^T)
template<int K, int IN_MODE, int B_NK, int OUT_RELU, int HAS_BIAS_OUT>
__global__ __launch_bounds__(256) void gemm_kernel(
    const float* __restrict__ A,
    const float* __restrict__ B,
    const float* __restrict__ bias_in,
    const float* __restrict__ bias_out,
    const int* __restrict__ deg,
    float* __restrict__ C,
    int nRows, int nColsTotal)
{
    __shared__ float As[64][64];    // 16 KB
    __shared__ float Bs[64][128];   // 32 KB
    __shared__ float rowscale[64];

    const int tid = threadIdx.x;
    const int cg = tid & 31;        // col group: owns cols 4*cg..4*cg+3
    const int rg = tid >> 5;        // row group: owns rows rg*8..rg*8+7
    const int row0 = blockIdx.x * 64;
    const int col0 = blockIdx.y * 128;

    if (IN_MODE >= 1) {
        if (tid < 64) {
            int r = row0 + tid;
            int dv = (r < nRows) ? deg[r] : 1;
            rowscale[tid] = rsqrtf((float)max(dv, 1));
        }
    }

    float acc[8][4];
#pragma unroll
    for (int i = 0; i < 8; ++i)
#pragma unroll
        for (int j = 0; j < 4; ++j) acc[i][j] = 0.f;

    for (int k0 = 0; k0 < K; k0 += 64) {
        __syncthreads();
        // ---- stage A chunk: 64 rows x 64 k = 1024 float4, 4 per thread
#pragma unroll
        for (int j = 0; j < 4; ++j) {
            int t4 = tid + j * 256;
            int ar = t4 >> 4;            // 0..63 tile row
            int ak = (t4 & 15) << 2;     // 0..60 k offset (float4)
            int grow = row0 + ar;
            float4 v = make_float4(0.f, 0.f, 0.f, 0.f);
            if (grow < nRows)
                v = *(const float4*)&A[(size_t)grow * K + k0 + ak];
            if (IN_MODE == 1) {
                float s = rowscale[ar];
                v.x *= s; v.y *= s; v.z *= s; v.w *= s;
            } else if (IN_MODE == 2) {
                float s = rowscale[ar];
                float4 bc = *(const float4*)&bias_in[k0 + ak];
                v.x = fmaxf(fmaf(v.x, s, bc.x), 0.f);
                v.y = fmaxf(fmaf(v.y, s, bc.y), 0.f);
                v.z = fmaxf(fmaf(v.z, s, bc.z), 0.f);
                v.w = fmaxf(fmaf(v.w, s, bc.w), 0.f);
            }
            *(float4*)&As[ar][ak] = v;
        }
        // ---- stage B chunk: 64 k x 128 cols
        if (B_NK) {
            // B[nColsTotal][K]; Bs[k][c] = B[col0+c][k0+k]. B is small (<=128KB),
            // stays L2-hot; uncoalesced reads acceptable.
#pragma unroll
            for (int j = 0; j < 8; ++j) {
                int t4 = tid + j * 256;          // 0..2047
                int c  = t4 & 127;
                int kq = (t4 >> 7) << 2;         // 0,4,...,60
                float4 v = *(const float4*)&B[(size_t)(col0 + c) * K + k0 + kq];
                Bs[kq + 0][c] = v.x;
                Bs[kq + 1][c] = v.y;
                Bs[kq + 2][c] = v.z;
                Bs[kq + 3][c] = v.w;
            }
        } else {
            // B[K][nColsTotal] contiguous rows; coalesced float4 loads.
#pragma unroll
            for (int j = 0; j < 8; ++j) {
                int t4 = tid + j * 256;
                int kr = t4 >> 5;                // 0..63
                int cq = (t4 & 31) << 2;         // 0..124
                float4 v = *(const float4*)&B[(size_t)(k0 + kr) * nColsTotal + col0 + cq];
                *(float4*)&Bs[kr][cq] = v;
            }
        }
        __syncthreads();

        // ---- compute: 64 k-steps, 32 FMAs each
#pragma unroll 8
        for (int k = 0; k < 64; ++k) {
            float4 bv = *(const float4*)&Bs[k][cg << 2];
#pragma unroll
            for (int ri = 0; ri < 8; ++ri) {
                float a = As[rg * 8 + ri][k];
                acc[ri][0] = fmaf(a, bv.x, acc[ri][0]);
                acc[ri][1] = fmaf(a, bv.y, acc[ri][1]);
                acc[ri][2] = fmaf(a, bv.z, acc[ri][2]);
                acc[ri][3] = fmaf(a, bv.w, acc[ri][3]);
            }
        }
    }

    // ---- epilogue
    float4 bo = make_float4(0.f, 0.f, 0.f, 0.f);
    if (HAS_BIAS_OUT)
        bo = *(const float4*)&bias_out[col0 + (cg << 2)];
#pragma unroll
    for (int ri = 0; ri < 8; ++ri) {
        int grow = row0 + rg * 8 + ri;
        if (grow < nRows) {
            float4 o;
            o.x = acc[ri][0] + bo.x;
            o.y = acc[ri][1] + bo.y;
            o.z = acc[ri][2] + bo.z;
            o.w = acc[ri][3] + bo.w;
            if (OUT_RELU) {
                o.x = fmaxf(o.x, 0.f); o.y = fmaxf(o.y, 0.f);
                o.z = fmaxf(o.z, 0.f); o.w = fmaxf(o.w, 0.f);
            }
            *(float4*)&C[(size_t)grow * nColsTotal + col0 + (cg << 2)] = o;
        }
    }
}

// ---------------------------------------------------------------------------
// Kernel 3: segmented scatter-add over dst-sorted edges.
// One wave per 128-edge contiguous chunk; lane owns channels {2l, 2l+1}.
// Run-length accumulate in registers; flush with atomics on dst change
// (chunk boundaries may split a segment, so atomics are required).
constexpr int EDGES_PER_WAVE = 128;

__global__ __launch_bounds__(256) void scatter_kernel(
    const float* __restrict__ h1, const int* __restrict__ src,
    const int* __restrict__ dst, float* __restrict__ acc, int nE)
{
    int wave = (blockIdx.x * 256 + threadIdx.x) >> 6;
    int lane = threadIdx.x & 63;
    int e0 = wave * EDGES_PER_WAVE;
    if (e0 >= nE) return;
    int e1 = min(e0 + EDGES_PER_WAVE, nE);

    float a0 = 0.f, a1 = 0.f;
    int cur = dst[e0];
    for (int e = e0; e < e1; ++e) {
        int d = dst[e];
        int s = src[e];
        if (d != cur) {
            atomicAdd(&acc[(size_t)cur * 128 + 2 * lane], a0);
            atomicAdd(&acc[(size_t)cur * 128 + 2 * lane + 1], a1);
            a0 = 0.f; a1 = 0.f;
            cur = d;
        }
        const float2 v = *(const float2*)&h1[(size_t)s * 128 + 2 * lane];
        a0 += v.x;
        a1 += v.y;
    }
    atomicAdd(&acc[(size_t)cur * 128 + 2 * lane], a0);
    atomicAdd(&acc[(size_t)cur * 128 + 2 * lane + 1], a1);
}

// ---------------------------------------------------------------------------
extern "C" void kernel_launch(void* const* d_in, const int* in_sizes, int n_in,
                              void* d_out, int out_size, void* d_ws, size_t ws_size,
                              hipStream_t stream)
{
    const float* x      = (const float*)d_in[0];
    const int*   src    = (const int*)d_in[1];
    const int*   dst    = (const int*)d_in[2];
    const float* W_conv = (const float*)d_in[3];
    const float* b_conv = (const float*)d_in[4];
    const float* W1     = (const float*)d_in[5];
    const float* b1     = (const float*)d_in[6];
    const float* W2     = (const float*)d_in[7];
    const float* b2     = (const float*)d_in[8];
    float* out = (float*)d_out;

    const int N  = in_sizes[0] / 256;   // 100000
    const int nE = in_sizes[1];         // 1600000

    // ws layout: h1 [N*128] | acc [N*128] | outdeg [N] | indeg [N]
    float* h1   = (float*)d_ws;
    float* accb = h1 + (size_t)N * 128;
    int*   outdeg = (int*)(accb + (size_t)N * 128);
    int*   indeg  = outdeg + N;

    // zero acc + both degree arrays (contiguous)
    hipMemsetAsync(accb, 0, ((size_t)N * 128 + 2 * (size_t)N) * sizeof(float), stream);

    deg_kernel<<<2048, 256, 0, stream>>>(src, dst, outdeg, indeg, nE);

    dim3 g1((N + 63) / 64, 1);
    // h1 = (x * rsqrt(outdeg)) @ W_conv
    gemm_kernel<256, 1, 0, 0, 0><<<g1, 256, 0, stream>>>(
        x, W_conv, nullptr, nullptr, outdeg, h1, N, 128);

    int waves  = (nE + EDGES_PER_WAVE - 1) / EDGES_PER_WAVE;
    int sblocks = (waves + 3) / 4;
    scatter_kernel<<<sblocks, 256, 0, stream>>>(h1, src, dst, accb, nE);

    // h3 = relu( relu(acc*rsqrt(indeg)+b_conv) @ W1^T + b1 )   (into h1 buffer)
    gemm_kernel<128, 2, 1, 1, 1><<<g1, 256, 0, stream>>>(
        accb, W1, b_conv, b1, indeg, h1, N, 128);

    // out = h3 @ W2^T + b2
    dim3 g3((N + 63) / 64, 2);
    gemm_kernel<128, 0, 1, 0, 1><<<g3, 256, 0, stream>>>(
        h1, W2, nullptr, b2, nullptr, out, N, 256);
}

// Round 2
// 477.526 us; speedup vs baseline: 1.3020x; 1.3020x over previous
//
#include <hip/hip_runtime.h>
#include <hip/hip_bf16.h>

// N=100000 nodes, E=1.6M edges (dst-sorted), IN_C=256, HID_C=128, OUT_C=256.
// All float32; src/dst int32.

// ---------------------------------------------------------------------------
// Kernel 1: out-degree counts via atomics (in-degree comes free from row_ptr).
__global__ __launch_bounds__(256) void deg_kernel(
    const int* __restrict__ src, int* __restrict__ outdeg, int nE)
{
    int i = blockIdx.x * 256 + threadIdx.x;
    int stride = gridDim.x * 256;
    for (; i < nE; i += stride)
        atomicAdd(&outdeg[src[i]], 1);
}

// ---------------------------------------------------------------------------
// Kernel 1b: row_ptr[n] = lower_bound(dst, n), exploiting sorted dst.
// Each boundary e (dst[e-1] != dst[e]) fills the gap nodes. Every entry of
// row_ptr[0..N] is written exactly once.
__global__ __launch_bounds__(256) void rowptr_kernel(
    const int* __restrict__ dst, int* __restrict__ row_ptr, int nE, int N)
{
    int e = blockIdx.x * 256 + threadIdx.x;
    if (e >= nE) return;
    int d = dst[e];
    if (e == 0) {
        for (int n = 0; n <= d; ++n) row_ptr[n] = 0;
    } else {
        int p = dst[e - 1];
        for (int n = p + 1; n <= d; ++n) row_ptr[n] = e;
    }
    if (e == nE - 1) {
        for (int n = d + 1; n <= N; ++n) row_ptr[n] = nE;
    }
}

// ---------------------------------------------------------------------------
// Kernel 2: tiled f32 GEMM, 64 rows x 128 cols per block, 256 threads,
// 8x4 register tile, K staged in 64-wide chunks, 4-k-blocked float4 LDS reads.
//
// IN_MODE: 0 = A as-is, 1 = A row scaled by rsqrt(max(deg,1))
// B_NK:    0 = B is [K][nColsTotal], 1 = B is [nColsTotal][K] (C = A @ B^T)
template<int K, int IN_MODE, int B_NK, int OUT_RELU, int HAS_BIAS_OUT>
__global__ __launch_bounds__(256) void gemm_kernel(
    const float* __restrict__ A,
    const float* __restrict__ B,
    const float* __restrict__ bias_out,
    const int* __restrict__ deg,
    float* __restrict__ C,
    int nRows, int nColsTotal)
{
    __shared__ float As[64][64];    // 16 KB
    __shared__ float Bs[64][128];   // 32 KB
    __shared__ float rowscale[64];

    const int tid = threadIdx.x;
    const int cg = tid & 31;        // owns cols 4*cg..4*cg+3
    const int rg = tid >> 5;        // owns rows rg*8..rg*8+7
    const int row0 = blockIdx.x * 64;
    const int col0 = blockIdx.y * 128;

    if (IN_MODE == 1) {
        if (tid < 64) {
            int r = row0 + tid;
            int dv = (r < nRows) ? deg[r] : 1;
            rowscale[tid] = rsqrtf((float)max(dv, 1));
        }
    }

    float acc[8][4];
#pragma unroll
    for (int i = 0; i < 8; ++i)
#pragma unroll
        for (int j = 0; j < 4; ++j) acc[i][j] = 0.f;

    for (int k0 = 0; k0 < K; k0 += 64) {
        __syncthreads();
        // ---- stage A chunk: 64 rows x 64 k
#pragma unroll
        for (int j = 0; j < 4; ++j) {
            int t4 = tid + j * 256;
            int ar = t4 >> 4;            // tile row
            int ak = (t4 & 15) << 2;     // k offset (float4)
            int grow = row0 + ar;
            float4 v = make_float4(0.f, 0.f, 0.f, 0.f);
            if (grow < nRows)
                v = *(const float4*)&A[(size_t)grow * K + k0 + ak];
            if (IN_MODE == 1) {
                float s = rowscale[ar];
                v.x *= s; v.y *= s; v.z *= s; v.w *= s;
            }
            *(float4*)&As[ar][ak] = v;
        }
        // ---- stage B chunk: 64 k x 128 cols
        if (B_NK) {
#pragma unroll
            for (int j = 0; j < 8; ++j) {
                int t4 = tid + j * 256;          // 0..2047
                int c  = t4 & 127;
                int kq = (t4 >> 7) << 2;
                float4 v = *(const float4*)&B[(size_t)(col0 + c) * K + k0 + kq];
                Bs[kq + 0][c] = v.x;
                Bs[kq + 1][c] = v.y;
                Bs[kq + 2][c] = v.z;
                Bs[kq + 3][c] = v.w;
            }
        } else {
#pragma unroll
            for (int j = 0; j < 8; ++j) {
                int t4 = tid + j * 256;
                int kr = t4 >> 5;
                int cq = (t4 & 31) << 2;
                float4 v = *(const float4*)&B[(size_t)(k0 + kr) * nColsTotal + col0 + cq];
                *(float4*)&Bs[kr][cq] = v;
            }
        }
        __syncthreads();

        // ---- compute: 4-k blocks; As via b128 (broadcast-class), Bs via b128
#pragma unroll
        for (int k = 0; k < 64; k += 4) {
            float4 a4[8];
#pragma unroll
            for (int ri = 0; ri < 8; ++ri)
                a4[ri] = *(const float4*)&As[rg * 8 + ri][k];
#pragma unroll
            for (int kk = 0; kk < 4; ++kk) {
                float4 bv = *(const float4*)&Bs[k + kk][cg << 2];
#pragma unroll
                for (int ri = 0; ri < 8; ++ri) {
                    float a = ((const float*)&a4[ri])[kk];
                    acc[ri][0] = fmaf(a, bv.x, acc[ri][0]);
                    acc[ri][1] = fmaf(a, bv.y, acc[ri][1]);
                    acc[ri][2] = fmaf(a, bv.z, acc[ri][2]);
                    acc[ri][3] = fmaf(a, bv.w, acc[ri][3]);
                }
            }
        }
    }

    // ---- epilogue
    float4 bo = make_float4(0.f, 0.f, 0.f, 0.f);
    if (HAS_BIAS_OUT)
        bo = *(const float4*)&bias_out[col0 + (cg << 2)];
#pragma unroll
    for (int ri = 0; ri < 8; ++ri) {
        int grow = row0 + rg * 8 + ri;
        if (grow < nRows) {
            float4 o;
            o.x = acc[ri][0] + bo.x;
            o.y = acc[ri][1] + bo.y;
            o.z = acc[ri][2] + bo.z;
            o.w = acc[ri][3] + bo.w;
            if (OUT_RELU) {
                o.x = fmaxf(o.x, 0.f); o.y = fmaxf(o.y, 0.f);
                o.z = fmaxf(o.z, 0.f); o.w = fmaxf(o.w, 0.f);
            }
            *(float4*)&C[(size_t)grow * nColsTotal + col0 + (cg << 2)] = o;
        }
    }
}

// ---------------------------------------------------------------------------
// Kernel 3: CSR gather — one wave per dst node, no atomics.
// Fuses dst-side normalization + b_conv + ReLU:
//   h2[n] = relu( (sum_{e in [row_ptr[n],row_ptr[n+1])} h1[src[e]]) *
//                 rsqrt(max(indeg,1)) + b_conv )
__global__ __launch_bounds__(256) void gather_kernel(
    const float* __restrict__ h1, const int* __restrict__ src,
    const int* __restrict__ row_ptr, const float* __restrict__ b_conv,
    float* __restrict__ h2, int N)
{
    int n = (blockIdx.x * 256 + threadIdx.x) >> 6;
    int lane = threadIdx.x & 63;
    if (n >= N) return;
    int e0 = row_ptr[n], e1 = row_ptr[n + 1];

    float a0 = 0.f, a1 = 0.f;
    int e = e0;
    for (; e + 1 < e1; e += 2) {
        int s0 = src[e], s1 = src[e + 1];
        float2 v0 = *(const float2*)&h1[(size_t)s0 * 128 + 2 * lane];
        float2 v1 = *(const float2*)&h1[(size_t)s1 * 128 + 2 * lane];
        a0 += v0.x + v1.x;
        a1 += v0.y + v1.y;
    }
    if (e < e1) {
        int s0 = src[e];
        float2 v0 = *(const float2*)&h1[(size_t)s0 * 128 + 2 * lane];
        a0 += v0.x;
        a1 += v0.y;
    }

    float sc = rsqrtf((float)max(e1 - e0, 1));
    float2 bc = *(const float2*)&b_conv[2 * lane];
    float2 o;
    o.x = fmaxf(fmaf(a0, sc, bc.x), 0.f);
    o.y = fmaxf(fmaf(a1, sc, bc.y), 0.f);
    *(float2*)&h2[(size_t)n * 128 + 2 * lane] = o;
}

// ---------------------------------------------------------------------------
extern "C" void kernel_launch(void* const* d_in, const int* in_sizes, int n_in,
                              void* d_out, int out_size, void* d_ws, size_t ws_size,
                              hipStream_t stream)
{
    const float* x      = (const float*)d_in[0];
    const int*   src    = (const int*)d_in[1];
    const int*   dst    = (const int*)d_in[2];
    const float* W_conv = (const float*)d_in[3];
    const float* b_conv = (const float*)d_in[4];
    const float* W1     = (const float*)d_in[5];
    const float* b1     = (const float*)d_in[6];
    const float* W2     = (const float*)d_in[7];
    const float* b2     = (const float*)d_in[8];
    float* out = (float*)d_out;

    const int N  = in_sizes[0] / 256;   // 100000
    const int nE = in_sizes[1];         // 1600000

    // ws layout: h1 [N*128] | h2 [N*128] | outdeg [N] | row_ptr [N+1]
    float* h1 = (float*)d_ws;
    float* h2 = h1 + (size_t)N * 128;
    int*   outdeg  = (int*)(h2 + (size_t)N * 128);
    int*   row_ptr = outdeg + N;

    hipMemsetAsync(outdeg, 0, (size_t)N * sizeof(int), stream);

    deg_kernel<<<2048, 256, 0, stream>>>(src, outdeg, nE);
    rowptr_kernel<<<(nE + 255) / 256, 256, 0, stream>>>(dst, row_ptr, nE, N);

    dim3 g1((N + 63) / 64, 1);
    // h1 = (x * rsqrt(outdeg)) @ W_conv
    gemm_kernel<256, 1, 0, 0, 0><<<g1, 256, 0, stream>>>(
        x, W_conv, nullptr, outdeg, h1, N, 128);

    // h2 = relu(csr_sum(h1) * rsqrt(indeg) + b_conv)   — no atomics
    gather_kernel<<<(N * 64 + 255) / 256, 256, 0, stream>>>(
        h1, src, row_ptr, b_conv, h2, N);

    // h3 = relu(h2 @ W1^T + b1)  (into h1 buffer)
    gemm_kernel<128, 0, 1, 1, 1><<<g1, 256, 0, stream>>>(
        h2, W1, b1, nullptr, h1, N, 128);

    // out = h3 @ W2^T + b2
    dim3 g3((N + 63) / 64, 2);
    gemm_kernel<128, 0, 1, 0, 1><<<g3, 256, 0, stream>>>(
        h1, W2, b2, nullptr, out, N, 256);
}

// Round 3
// 245.792 us; speedup vs baseline: 2.5295x; 1.9428x over previous
//
#include <hip/hip_runtime.h>
#include <hip/hip_bf16.h>

// N=100000 nodes, E=1.6M edges (dst-sorted), IN_C=256, HID_C=128, OUT_C=256.
// f32 inputs; GEMMs run as bf16 MFMA with f32 accumulate.

typedef __attribute__((ext_vector_type(8))) short short8;
typedef __attribute__((ext_vector_type(4))) float f32x4;

static __device__ __forceinline__ float bf2f(unsigned int u16) {
    union { unsigned int i; float f; } c; c.i = u16 << 16; return c.f;
}
static __device__ __forceinline__ ushort f2bf(float f) {
    union { float f; unsigned int i; } c; c.f = f;
    unsigned int i = c.i;
    return (ushort)((i + 0x7FFFu + ((i >> 16) & 1u)) >> 16);   // RNE
}

// ---------------------------------------------------------------------------
__global__ __launch_bounds__(256) void deg_kernel(
    const int* __restrict__ src, int* __restrict__ outdeg, int nE)
{
    int i = blockIdx.x * 256 + threadIdx.x;
    int stride = gridDim.x * 256;
    for (; i < nE; i += stride)
        atomicAdd(&outdeg[src[i]], 1);
}

// row_ptr[n] = lower_bound(dst, n); dst is sorted.
__global__ __launch_bounds__(256) void rowptr_kernel(
    const int* __restrict__ dst, int* __restrict__ row_ptr, int nE, int N)
{
    int e = blockIdx.x * 256 + threadIdx.x;
    if (e >= nE) return;
    int d = dst[e];
    if (e == 0) {
        for (int n = 0; n <= d; ++n) row_ptr[n] = 0;
    } else {
        int p = dst[e - 1];
        for (int n = p + 1; n <= d; ++n) row_ptr[n] = e;
    }
    if (e == nE - 1) {
        for (int n = d + 1; n <= N; ++n) row_ptr[n] = nE;
    }
}

// ---------------------------------------------------------------------------
// Weight prep: W_convT[o][k] = bf16(W_conv[k][o]); W1b, W2b = bf16 copies.
// All end up [out][K] row-major bf16 so one staging path serves all GEMMs.
__global__ __launch_bounds__(256) void wprep_kernel(
    const float* __restrict__ Wc, const float* __restrict__ W1,
    const float* __restrict__ W2, ushort* __restrict__ WcT,
    ushort* __restrict__ W1b, ushort* __restrict__ W2b)
{
    int i = blockIdx.x * 256 + threadIdx.x;
    if (i < 128 * 256) {
        int o = i >> 8, k = i & 255;
        WcT[o * 256 + k] = f2bf(Wc[k * 128 + o]);
    } else if (i < 128 * 256 + 128 * 128) {
        int j = i - 128 * 256;
        W1b[j] = f2bf(W1[j]);
    } else if (i < 128 * 256 + 128 * 128 + 256 * 128) {
        int j = i - 128 * 256 - 128 * 128;
        W2b[j] = f2bf(W2[j]);
    }
}

// ---------------------------------------------------------------------------
// bf16 MFMA GEMM: C[nRows][nColsTotal] = op(A) @ B^T (+bias, relu).
// Block = 64 rows x 128 cols, 4 waves; wave w owns rows w*16..w*16+15, all
// 128 cols as 8 16x16 C-tiles. K staged in 64-chunks; LDS tiles stored as
// [row][K] bf16 with 16B-slot XOR swizzle (slot ^= row&7) so fragment reads
// (16 lanes at stride 128B) are bank-conflict-free.
// A_BF16: A global is bf16 (else f32). IN_SCALE: rows scaled by
// rsqrt(max(deg,1)) before rounding. B is [colTotal][K] bf16.
template<int K, int A_BF16, int IN_SCALE, int OUT_RELU, int HAS_BIAS, int OUT_BF16>
__global__ __launch_bounds__(256) void mgemm_kernel(
    const void* __restrict__ Av, const ushort* __restrict__ B,
    const float* __restrict__ bias, const int* __restrict__ deg,
    void* __restrict__ Cv, int nRows, int nColsTotal)
{
    __shared__ ushort As[64 * 64];    // 8 KB
    __shared__ ushort Bs[128 * 64];   // 16 KB
    __shared__ float rowscale[64];

    const int tid  = threadIdx.x;
    const int lane = tid & 63;
    const int w    = tid >> 6;        // wave 0..3
    const int r    = lane & 15;
    const int q    = lane >> 4;       // 0..3
    const int row0 = blockIdx.x * 64;
    const int col0 = blockIdx.y * 128;

    if (IN_SCALE && tid < 64) {
        int g = row0 + tid;
        int dv = (g < nRows) ? deg[g] : 1;
        rowscale[tid] = rsqrtf((float)max(dv, 1));
    }

    f32x4 acc[8];
#pragma unroll
    for (int t = 0; t < 8; ++t) acc[t] = (f32x4){0.f, 0.f, 0.f, 0.f};

    for (int k0 = 0; k0 < K; k0 += 64) {
        __syncthreads();
        // ---- stage A: 64 rows x 64 k (2 slots of 8 bf16 per thread)
#pragma unroll
        for (int s = 0; s < 2; ++s) {
            int idx = s * 256 + tid;
            int row = idx >> 3, kg = idx & 7;
            int g = row0 + row;
            int lidx = row * 64 + ((kg ^ (row & 7)) * 8);
            if (A_BF16) {
                const ushort* A = (const ushort*)Av;
                short8 v = (short8){0, 0, 0, 0, 0, 0, 0, 0};
                if (g < nRows)
                    v = *(const short8*)&A[(size_t)g * K + k0 + kg * 8];
                *(short8*)&As[lidx] = v;
            } else {
                const float* A = (const float*)Av;
                float4 v0 = make_float4(0.f, 0.f, 0.f, 0.f), v1 = v0;
                if (g < nRows) {
                    v0 = *(const float4*)&A[(size_t)g * K + k0 + kg * 8];
                    v1 = *(const float4*)&A[(size_t)g * K + k0 + kg * 8 + 4];
                }
                if (IN_SCALE) {
                    float sc = rowscale[row];
                    v0.x *= sc; v0.y *= sc; v0.z *= sc; v0.w *= sc;
                    v1.x *= sc; v1.y *= sc; v1.z *= sc; v1.w *= sc;
                }
                ushort u[8];
                u[0] = f2bf(v0.x); u[1] = f2bf(v0.y); u[2] = f2bf(v0.z); u[3] = f2bf(v0.w);
                u[4] = f2bf(v1.x); u[5] = f2bf(v1.y); u[6] = f2bf(v1.z); u[7] = f2bf(v1.w);
                *(short8*)&As[lidx] = *(const short8*)u;
            }
        }
        // ---- stage B: 128 cols x 64 k (4 slots per thread), bf16 source
#pragma unroll
        for (int s = 0; s < 4; ++s) {
            int idx = s * 256 + tid;
            int col = idx >> 3, kg = idx & 7;
            *(short8*)&Bs[col * 64 + ((kg ^ (col & 7)) * 8)] =
                *(const short8*)&B[(size_t)(col0 + col) * K + k0 + kg * 8];
        }
        __syncthreads();

        // ---- compute: 2 K-steps of 32; per step 1 A-frag + 8 B-frag + 8 MFMA
#pragma unroll
        for (int ks = 0; ks < 2; ++ks) {
            int arow = w * 16 + r;
            short8 af = *(const short8*)&As[arow * 64 + (((ks * 4 + q) ^ (r & 7)) * 8)];
#pragma unroll
            for (int t = 0; t < 8; ++t) {
                short8 bf = *(const short8*)&Bs[(t * 16 + r) * 64 + (((ks * 4 + q) ^ (r & 7)) * 8)];
                acc[t] = __builtin_amdgcn_mfma_f32_16x16x32_bf16(af, bf, acc[t], 0, 0, 0);
            }
        }
    }

    // ---- epilogue: C/D layout col=lane&15, row=(lane>>4)*4+reg
#pragma unroll
    for (int t = 0; t < 8; ++t) {
        int col = col0 + t * 16 + r;
        float bo = HAS_BIAS ? bias[col] : 0.f;
#pragma unroll
        for (int reg = 0; reg < 4; ++reg) {
            int g = row0 + w * 16 + q * 4 + reg;
            if (g < nRows) {
                float v = acc[t][reg] + bo;
                if (OUT_RELU) v = fmaxf(v, 0.f);
                if (OUT_BF16)
                    ((ushort*)Cv)[(size_t)g * nColsTotal + col] = f2bf(v);
                else
                    ((float*)Cv)[(size_t)g * nColsTotal + col] = v;
            }
        }
    }
}

// ---------------------------------------------------------------------------
// CSR gather over bf16 h1; fuses rsqrt(indeg)+b_conv+ReLU; bf16 out.
__global__ __launch_bounds__(256) void gather_kernel(
    const ushort* __restrict__ h1, const int* __restrict__ src,
    const int* __restrict__ rp, const float* __restrict__ b_conv,
    ushort* __restrict__ h2, int N)
{
    int n = (blockIdx.x * 256 + threadIdx.x) >> 6;
    int lane = threadIdx.x & 63;
    if (n >= N) return;
    int e0 = rp[n], e1 = rp[n + 1];

    float a0 = 0.f, a1 = 0.f;
    int e = e0;
    for (; e + 3 < e1; e += 4) {
        int s0 = src[e], s1 = src[e + 1], s2 = src[e + 2], s3 = src[e + 3];
        unsigned int v0 = *(const unsigned int*)&h1[(size_t)s0 * 128 + 2 * lane];
        unsigned int v1 = *(const unsigned int*)&h1[(size_t)s1 * 128 + 2 * lane];
        unsigned int v2 = *(const unsigned int*)&h1[(size_t)s2 * 128 + 2 * lane];
        unsigned int v3 = *(const unsigned int*)&h1[(size_t)s3 * 128 + 2 * lane];
        a0 += bf2f(v0 & 0xffff) + bf2f(v1 & 0xffff) + bf2f(v2 & 0xffff) + bf2f(v3 & 0xffff);
        a1 += bf2f(v0 >> 16)    + bf2f(v1 >> 16)    + bf2f(v2 >> 16)    + bf2f(v3 >> 16);
    }
    for (; e < e1; ++e) {
        unsigned int v = *(const unsigned int*)&h1[(size_t)src[e] * 128 + 2 * lane];
        a0 += bf2f(v & 0xffff);
        a1 += bf2f(v >> 16);
    }

    float sc = rsqrtf((float)max(e1 - e0, 1));
    float2 bc = *(const float2*)&b_conv[2 * lane];
    ushort o0 = f2bf(fmaxf(fmaf(a0, sc, bc.x), 0.f));
    ushort o1 = f2bf(fmaxf(fmaf(a1, sc, bc.y), 0.f));
    *(unsigned int*)&h2[(size_t)n * 128 + 2 * lane] = (unsigned int)o0 | ((unsigned int)o1 << 16);
}

// ---------------------------------------------------------------------------
extern "C" void kernel_launch(void* const* d_in, const int* in_sizes, int n_in,
                              void* d_out, int out_size, void* d_ws, size_t ws_size,
                              hipStream_t stream)
{
    const float* x      = (const float*)d_in[0];
    const int*   src    = (const int*)d_in[1];
    const int*   dst    = (const int*)d_in[2];
    const float* W_conv = (const float*)d_in[3];
    const float* b_conv = (const float*)d_in[4];
    const float* W1     = (const float*)d_in[5];
    const float* b1     = (const float*)d_in[6];
    const float* W2     = (const float*)d_in[7];
    const float* b2     = (const float*)d_in[8];
    float* out = (float*)d_out;

    const int N  = in_sizes[0] / 256;   // 100000
    const int nE = in_sizes[1];         // 1600000

    // ws layout (ushort units unless noted):
    // h1 [N*128] | h2 [N*128] | WcT [128*256] | W1b [128*128] | W2b [256*128]
    // | outdeg [N int] | row_ptr [N+1 int]
    ushort* h1  = (ushort*)d_ws;
    ushort* h2  = h1 + (size_t)N * 128;
    ushort* WcT = h2 + (size_t)N * 128;
    ushort* W1b = WcT + 128 * 256;
    ushort* W2b = W1b + 128 * 128;
    int* outdeg = (int*)(W2b + 256 * 128);
    int* rp     = outdeg + N;

    hipMemsetAsync(outdeg, 0, (size_t)N * sizeof(int), stream);

    deg_kernel<<<2048, 256, 0, stream>>>(src, outdeg, nE);
    rowptr_kernel<<<(nE + 255) / 256, 256, 0, stream>>>(dst, rp, nE, N);
    wprep_kernel<<<(128 * 256 + 128 * 128 + 256 * 128 + 255) / 256, 256, 0, stream>>>(
        W_conv, W1, W2, WcT, W1b, W2b);

    dim3 g1((N + 63) / 64, 1);
    // h1 = bf16[(x * rsqrt(outdeg)) @ W_conv]
    mgemm_kernel<256, 0, 1, 0, 0, 1><<<g1, 256, 0, stream>>>(
        x, WcT, nullptr, outdeg, h1, N, 128);

    // h2 = bf16[relu(csr_sum(h1) * rsqrt(indeg) + b_conv)]
    gather_kernel<<<(N * 64 + 255) / 256, 256, 0, stream>>>(
        h1, src, rp, b_conv, h2, N);

    // h3 = bf16[relu(h2 @ W1^T + b1)]  (reuses h1 buffer)
    mgemm_kernel<128, 1, 0, 1, 1, 1><<<g1, 256, 0, stream>>>(
        h2, W1b, b1, nullptr, h1, N, 128);

    // out = f32[h3 @ W2^T + b2]
    dim3 g3((N + 63) / 64, 2);
    mgemm_kernel<128, 1, 0, 0, 1, 0><<<g3, 256, 0, stream>>>(
        h1, W2b, b2, nullptr, out, N, 256);
}

// Round 4
// 231.562 us; speedup vs baseline: 2.6849x; 1.0615x over previous
//
#include <hip/hip_runtime.h>
#include <hip/hip_bf16.h>

// N=100000 nodes, E=1.6M edges (dst-sorted), IN_C=256, HID_C=128, OUT_C=256.
// f32 inputs; GEMMs run as bf16 MFMA with f32 accumulate.

typedef __attribute__((ext_vector_type(8))) short short8;
typedef __attribute__((ext_vector_type(4))) float f32x4;

static __device__ __forceinline__ float bf2f(unsigned int u16) {
    union { unsigned int i; float f; } c; c.i = u16 << 16; return c.f;
}
static __device__ __forceinline__ ushort f2bf(float f) {
    union { float f; unsigned int i; } c; c.f = f;
    unsigned int i = c.i;
    return (ushort)((i + 0x7FFFu + ((i >> 16) & 1u)) >> 16);   // RNE
}

// ---------------------------------------------------------------------------
__global__ __launch_bounds__(256) void deg_kernel(
    const int* __restrict__ src, int* __restrict__ outdeg, int nE)
{
    int i = blockIdx.x * 256 + threadIdx.x;
    int stride = gridDim.x * 256;
    for (; i < nE; i += stride)
        atomicAdd(&outdeg[src[i]], 1);
}

// row_ptr[n] = lower_bound(dst, n); dst is sorted.
__global__ __launch_bounds__(256) void rowptr_kernel(
    const int* __restrict__ dst, int* __restrict__ row_ptr, int nE, int N)
{
    int e = blockIdx.x * 256 + threadIdx.x;
    if (e >= nE) return;
    int d = dst[e];
    if (e == 0) {
        for (int n = 0; n <= d; ++n) row_ptr[n] = 0;
    } else {
        int p = dst[e - 1];
        for (int n = p + 1; n <= d; ++n) row_ptr[n] = e;
    }
    if (e == nE - 1) {
        for (int n = d + 1; n <= N; ++n) row_ptr[n] = nE;
    }
}

// ---------------------------------------------------------------------------
// Weight prep: W_convT[o][k] = bf16(W_conv[k][o]); W1b, W2b = bf16 copies.
__global__ __launch_bounds__(256) void wprep_kernel(
    const float* __restrict__ Wc, const float* __restrict__ W1,
    const float* __restrict__ W2, ushort* __restrict__ WcT,
    ushort* __restrict__ W1b, ushort* __restrict__ W2b)
{
    int i = blockIdx.x * 256 + threadIdx.x;
    if (i < 128 * 256) {
        int o = i >> 8, k = i & 255;
        WcT[o * 256 + k] = f2bf(Wc[k * 128 + o]);
    } else if (i < 128 * 256 + 128 * 128) {
        int j = i - 128 * 256;
        W1b[j] = f2bf(W1[j]);
    } else if (i < 128 * 256 + 128 * 128 + 256 * 128) {
        int j = i - 128 * 256 - 128 * 128;
        W2b[j] = f2bf(W2[j]);
    }
}

// ---------------------------------------------------------------------------
// bf16 MFMA GEMM: C[nRows][nColsTotal] = op(A) @ B^T (+bias, relu).
// Block = 64 rows x 128 cols, 4 waves; wave w owns rows w*16..w*16+15 as 8
// 16x16 C-tiles. K staged in 64-chunks; LDS tiles [row][K] bf16 with 16B-slot
// XOR swizzle (slot ^= row&7) so fragment reads are bank-conflict-free.
template<int K, int A_BF16, int IN_SCALE, int OUT_RELU, int HAS_BIAS, int OUT_BF16>
__global__ __launch_bounds__(256) void mgemm_kernel(
    const void* __restrict__ Av, const ushort* __restrict__ B,
    const float* __restrict__ bias, const int* __restrict__ deg,
    void* __restrict__ Cv, int nRows, int nColsTotal)
{
    __shared__ ushort As[64 * 64];    // 8 KB
    __shared__ ushort Bs[128 * 64];   // 16 KB
    __shared__ float rowscale[64];

    const int tid  = threadIdx.x;
    const int lane = tid & 63;
    const int w    = tid >> 6;        // wave 0..3
    const int r    = lane & 15;
    const int q    = lane >> 4;       // 0..3
    const int row0 = blockIdx.x * 64;
    const int col0 = blockIdx.y * 128;

    if (IN_SCALE && tid < 64) {
        int g = row0 + tid;
        int dv = (g < nRows) ? deg[g] : 1;
        rowscale[tid] = rsqrtf((float)max(dv, 1));
    }

    f32x4 acc[8];
#pragma unroll
    for (int t = 0; t < 8; ++t) acc[t] = (f32x4){0.f, 0.f, 0.f, 0.f};

    for (int k0 = 0; k0 < K; k0 += 64) {
        __syncthreads();
        // ---- stage A: 64 rows x 64 k (2 slots of 8 bf16 per thread)
#pragma unroll
        for (int s = 0; s < 2; ++s) {
            int idx = s * 256 + tid;
            int row = idx >> 3, kg = idx & 7;
            int g = row0 + row;
            int lidx = row * 64 + ((kg ^ (row & 7)) * 8);
            if (A_BF16) {
                const ushort* A = (const ushort*)Av;
                short8 v = (short8){0, 0, 0, 0, 0, 0, 0, 0};
                if (g < nRows)
                    v = *(const short8*)&A[(size_t)g * K + k0 + kg * 8];
                *(short8*)&As[lidx] = v;
            } else {
                const float* A = (const float*)Av;
                float4 v0 = make_float4(0.f, 0.f, 0.f, 0.f), v1 = v0;
                if (g < nRows) {
                    v0 = *(const float4*)&A[(size_t)g * K + k0 + kg * 8];
                    v1 = *(const float4*)&A[(size_t)g * K + k0 + kg * 8 + 4];
                }
                if (IN_SCALE) {
                    float sc = rowscale[row];
                    v0.x *= sc; v0.y *= sc; v0.z *= sc; v0.w *= sc;
                    v1.x *= sc; v1.y *= sc; v1.z *= sc; v1.w *= sc;
                }
                ushort u[8];
                u[0] = f2bf(v0.x); u[1] = f2bf(v0.y); u[2] = f2bf(v0.z); u[3] = f2bf(v0.w);
                u[4] = f2bf(v1.x); u[5] = f2bf(v1.y); u[6] = f2bf(v1.z); u[7] = f2bf(v1.w);
                *(short8*)&As[lidx] = *(const short8*)u;
            }
        }
        // ---- stage B: 128 cols x 64 k (4 slots per thread), bf16 source
#pragma unroll
        for (int s = 0; s < 4; ++s) {
            int idx = s * 256 + tid;
            int col = idx >> 3, kg = idx & 7;
            *(short8*)&Bs[col * 64 + ((kg ^ (col & 7)) * 8)] =
                *(const short8*)&B[(size_t)(col0 + col) * K + k0 + kg * 8];
        }
        __syncthreads();

        // ---- compute: 2 K-steps of 32; per step 1 A-frag + 8 B-frag + 8 MFMA
#pragma unroll
        for (int ks = 0; ks < 2; ++ks) {
            int arow = w * 16 + r;
            short8 af = *(const short8*)&As[arow * 64 + (((ks * 4 + q) ^ (r & 7)) * 8)];
#pragma unroll
            for (int t = 0; t < 8; ++t) {
                short8 bf = *(const short8*)&Bs[(t * 16 + r) * 64 + (((ks * 4 + q) ^ (r & 7)) * 8)];
                acc[t] = __builtin_amdgcn_mfma_f32_16x16x32_bf16(af, bf, acc[t], 0, 0, 0);
            }
        }
    }

    // ---- epilogue: C/D layout col=lane&15, row=(lane>>4)*4+reg
#pragma unroll
    for (int t = 0; t < 8; ++t) {
        int col = col0 + t * 16 + r;
        float bo = HAS_BIAS ? bias[col] : 0.f;
#pragma unroll
        for (int reg = 0; reg < 4; ++reg) {
            int g = row0 + w * 16 + q * 4 + reg;
            if (g < nRows) {
                float v = acc[t][reg] + bo;
                if (OUT_RELU) v = fmaxf(v, 0.f);
                if (OUT_BF16)
                    ((ushort*)Cv)[(size_t)g * nColsTotal + col] = f2bf(v);
                else
                    ((float*)Cv)[(size_t)g * nColsTotal + col] = v;
            }
        }
    }
}

// ---------------------------------------------------------------------------
// CSR gather, 4 edges in flight per wave: lane = g*16 + c, group g (0..3)
// handles edges e0+g, e0+g+4, ...; channel slot c covers channels c*8..c*8+7
// (16B short8 loads). Cross-group combine via shfl_xor butterfly; lanes 0..15
// store the 256B output row. Fuses rsqrt(indeg) + b_conv + ReLU; bf16 out.
__global__ __launch_bounds__(256) void gather_kernel(
    const ushort* __restrict__ h1, const int* __restrict__ src,
    const int* __restrict__ rp, const float* __restrict__ b_conv,
    ushort* __restrict__ h2, int N)
{
    int n = (blockIdx.x * 256 + threadIdx.x) >> 6;
    int lane = threadIdx.x & 63;
    if (n >= N) return;
    const int g = lane >> 4;
    const int c = lane & 15;
    int e0 = rp[n], e1 = rp[n + 1];

    float a[8];
#pragma unroll
    for (int j = 0; j < 8; ++j) a[j] = 0.f;

    int e = e0 + g;
    for (; e + 4 < e1; e += 8) {           // 2 edges in flight per lane
        int s0 = src[e], s1 = src[e + 4];
        short8 v0 = *(const short8*)&h1[(size_t)s0 * 128 + c * 8];
        short8 v1 = *(const short8*)&h1[(size_t)s1 * 128 + c * 8];
#pragma unroll
        for (int j = 0; j < 8; ++j)
            a[j] += bf2f((unsigned short)v0[j]) + bf2f((unsigned short)v1[j]);
    }
    if (e < e1) {
        int s0 = src[e];
        short8 v0 = *(const short8*)&h1[(size_t)s0 * 128 + c * 8];
#pragma unroll
        for (int j = 0; j < 8; ++j)
            a[j] += bf2f((unsigned short)v0[j]);
    }

    // combine the 4 edge-groups: lanes l, l^16, l^32, l^48
#pragma unroll
    for (int j = 0; j < 8; ++j) {
        a[j] += __shfl_xor(a[j], 16, 64);
        a[j] += __shfl_xor(a[j], 32, 64);
    }

    if (g == 0) {
        float sc = rsqrtf((float)max(e1 - e0, 1));
        ushort o[8];
#pragma unroll
        for (int j = 0; j < 8; ++j)
            o[j] = f2bf(fmaxf(fmaf(a[j], sc, b_conv[c * 8 + j]), 0.f));
        *(short8*)&h2[(size_t)n * 128 + c * 8] = *(const short8*)o;
    }
}

// ---------------------------------------------------------------------------
extern "C" void kernel_launch(void* const* d_in, const int* in_sizes, int n_in,
                              void* d_out, int out_size, void* d_ws, size_t ws_size,
                              hipStream_t stream)
{
    const float* x      = (const float*)d_in[0];
    const int*   src    = (const int*)d_in[1];
    const int*   dst    = (const int*)d_in[2];
    const float* W_conv = (const float*)d_in[3];
    const float* b_conv = (const float*)d_in[4];
    const float* W1     = (const float*)d_in[5];
    const float* b1     = (const float*)d_in[6];
    const float* W2     = (const float*)d_in[7];
    const float* b2     = (const float*)d_in[8];
    float* out = (float*)d_out;

    const int N  = in_sizes[0] / 256;   // 100000
    const int nE = in_sizes[1];         // 1600000

    // ws layout (ushort units unless noted):
    // h1 [N*128] | h2 [N*128] | WcT [128*256] | W1b [128*128] | W2b [256*128]
    // | outdeg [N int] | row_ptr [N+1 int]
    ushort* h1  = (ushort*)d_ws;
    ushort* h2  = h1 + (size_t)N * 128;
    ushort* WcT = h2 + (size_t)N * 128;
    ushort* W1b = WcT + 128 * 256;
    ushort* W2b = W1b + 128 * 128;
    int* outdeg = (int*)(W2b + 256 * 128);
    int* rp     = outdeg + N;

    hipMemsetAsync(outdeg, 0, (size_t)N * sizeof(int), stream);

    deg_kernel<<<2048, 256, 0, stream>>>(src, outdeg, nE);
    rowptr_kernel<<<(nE + 255) / 256, 256, 0, stream>>>(dst, rp, nE, N);
    wprep_kernel<<<(128 * 256 + 128 * 128 + 256 * 128 + 255) / 256, 256, 0, stream>>>(
        W_conv, W1, W2, WcT, W1b, W2b);

    dim3 g1((N + 63) / 64, 1);
    // h1 = bf16[(x * rsqrt(outdeg)) @ W_conv]
    mgemm_kernel<256, 0, 1, 0, 0, 1><<<g1, 256, 0, stream>>>(
        x, WcT, nullptr, outdeg, h1, N, 128);

    // h2 = bf16[relu(csr_sum(h1) * rsqrt(indeg) + b_conv)]
    gather_kernel<<<(N * 64 + 255) / 256, 256, 0, stream>>>(
        h1, src, rp, b_conv, h2, N);

    // h3 = bf16[relu(h2 @ W1^T + b1)]  (reuses h1 buffer)
    mgemm_kernel<128, 1, 0, 1, 1, 1><<<g1, 256, 0, stream>>>(
        h2, W1b, b1, nullptr, h1, N, 128);

    // out = f32[h3 @ W2^T + b2]
    dim3 g3((N + 63) / 64, 2);
    mgemm_kernel<128, 1, 0, 0, 1, 0><<<g3, 256, 0, stream>>>(
        h1, W2b, b2, nullptr, out, N, 256);
}

// Round 5
// 215.027 us; speedup vs baseline: 2.8914x; 1.0769x over previous
//
#include <hip/hip_runtime.h>
#include <hip/hip_bf16.h>

// N=100000 nodes, E=1.6M edges (dst-sorted), IN_C=256, HID_C=128, OUT_C=256.
// f32 inputs; GEMMs run as bf16 MFMA with f32 accumulate.
// Pipeline: memset(outdeg) -> wprep -> gemm1(+fused deg atomics) -> rowptr
//           -> gather(per-edge rsqrt(outdeg) scale) -> gemm23 (fused).

typedef __attribute__((ext_vector_type(8))) short short8;
typedef __attribute__((ext_vector_type(4))) float f32x4;

static __device__ __forceinline__ float bf2f(unsigned int u16) {
    union { unsigned int i; float f; } c; c.i = u16 << 16; return c.f;
}
static __device__ __forceinline__ ushort f2bf(float f) {
    union { float f; unsigned int i; } c; c.f = f;
    unsigned int i = c.i;
    return (ushort)((i + 0x7FFFu + ((i >> 16) & 1u)) >> 16);   // RNE
}

// ---------------------------------------------------------------------------
// row_ptr[n] = lower_bound(dst, n); dst is sorted.
__global__ __launch_bounds__(256) void rowptr_kernel(
    const int* __restrict__ dst, int* __restrict__ row_ptr, int nE, int N)
{
    int e = blockIdx.x * 256 + threadIdx.x;
    if (e >= nE) return;
    int d = dst[e];
    if (e == 0) {
        for (int n = 0; n <= d; ++n) row_ptr[n] = 0;
    } else {
        int p = dst[e - 1];
        for (int n = p + 1; n <= d; ++n) row_ptr[n] = e;
    }
    if (e == nE - 1) {
        for (int n = d + 1; n <= N; ++n) row_ptr[n] = nE;
    }
}

// ---------------------------------------------------------------------------
// Weight prep: W_convT[o][k] = bf16(W_conv[k][o]); W1b, W2b = bf16 copies.
__global__ __launch_bounds__(256) void wprep_kernel(
    const float* __restrict__ Wc, const float* __restrict__ W1,
    const float* __restrict__ W2, ushort* __restrict__ WcT,
    ushort* __restrict__ W1b, ushort* __restrict__ W2b)
{
    int i = blockIdx.x * 256 + threadIdx.x;
    if (i < 128 * 256) {
        int o = i >> 8, k = i & 255;
        WcT[o * 256 + k] = f2bf(Wc[k * 128 + o]);
    } else if (i < 128 * 256 + 128 * 128) {
        int j = i - 128 * 256;
        W1b[j] = f2bf(W1[j]);
    } else if (i < 128 * 256 + 128 * 128 + 256 * 128) {
        int j = i - 128 * 256 - 128 * 128;
        W2b[j] = f2bf(W2[j]);
    }
}

// ---------------------------------------------------------------------------
// GEMM1: h1u[64 rows x 128 cols per block] = bf16[x @ W_conv] (unscaled) with
// the out-degree histogram fused in: each block also processes a 1024-edge
// slice with fire-and-forget atomics AFTER its epilogue, so the atomic drain
// hides under other blocks' MFMA work.
__global__ __launch_bounds__(256) void gemm1_kernel(
    const float* __restrict__ A, const ushort* __restrict__ B,
    const int* __restrict__ src, int* __restrict__ outdeg,
    ushort* __restrict__ C, int nRows, int nE)
{
    __shared__ ushort As[64 * 64];    // 8 KB
    __shared__ ushort Bs[128 * 64];   // 16 KB

    const int tid  = threadIdx.x;
    const int lane = tid & 63;
    const int w    = tid >> 6;
    const int r    = lane & 15;
    const int q    = lane >> 4;
    const int row0 = blockIdx.x * 64;

    f32x4 acc[8];
#pragma unroll
    for (int t = 0; t < 8; ++t) acc[t] = (f32x4){0.f, 0.f, 0.f, 0.f};

    for (int k0 = 0; k0 < 256; k0 += 64) {
        __syncthreads();
#pragma unroll
        for (int s = 0; s < 2; ++s) {
            int idx = s * 256 + tid;
            int row = idx >> 3, kg = idx & 7;
            int g = row0 + row;
            float4 v0 = make_float4(0.f, 0.f, 0.f, 0.f), v1 = v0;
            if (g < nRows) {
                v0 = *(const float4*)&A[(size_t)g * 256 + k0 + kg * 8];
                v1 = *(const float4*)&A[(size_t)g * 256 + k0 + kg * 8 + 4];
            }
            ushort u[8];
            u[0] = f2bf(v0.x); u[1] = f2bf(v0.y); u[2] = f2bf(v0.z); u[3] = f2bf(v0.w);
            u[4] = f2bf(v1.x); u[5] = f2bf(v1.y); u[6] = f2bf(v1.z); u[7] = f2bf(v1.w);
            *(short8*)&As[row * 64 + ((kg ^ (row & 7)) * 8)] = *(const short8*)u;
        }
#pragma unroll
        for (int s = 0; s < 4; ++s) {
            int idx = s * 256 + tid;
            int col = idx >> 3, kg = idx & 7;
            *(short8*)&Bs[col * 64 + ((kg ^ (col & 7)) * 8)] =
                *(const short8*)&B[(size_t)col * 256 + k0 + kg * 8];
        }
        __syncthreads();

#pragma unroll
        for (int ks = 0; ks < 2; ++ks) {
            short8 af = *(const short8*)&As[(w * 16 + r) * 64 + (((ks * 4 + q) ^ (r & 7)) * 8)];
#pragma unroll
            for (int t = 0; t < 8; ++t) {
                short8 bf = *(const short8*)&Bs[(t * 16 + r) * 64 + (((ks * 4 + q) ^ (r & 7)) * 8)];
                acc[t] = __builtin_amdgcn_mfma_f32_16x16x32_bf16(af, bf, acc[t], 0, 0, 0);
            }
        }
    }

#pragma unroll
    for (int t = 0; t < 8; ++t) {
        int col = t * 16 + r;
#pragma unroll
        for (int reg = 0; reg < 4; ++reg) {
            int g = row0 + w * 16 + q * 4 + reg;
            if (g < nRows)
                C[(size_t)g * 128 + col] = f2bf(acc[t][reg]);
        }
    }

    // ---- fused out-degree histogram (fire-and-forget, after epilogue)
    int base = blockIdx.x * 1024;
#pragma unroll
    for (int s = 0; s < 4; ++s) {
        int e = base + s * 256 + tid;
        if (e < nE) atomicAdd(&outdeg[src[e]], 1);
    }
}

// ---------------------------------------------------------------------------
// CSR gather, 4 edges in flight per wave; per-edge scale rsqrt(outdeg[src]).
// Fuses rsqrt(indeg) + b_conv + ReLU; bf16 out.
__global__ __launch_bounds__(256) void gather_kernel(
    const ushort* __restrict__ h1, const int* __restrict__ src,
    const int* __restrict__ rp, const int* __restrict__ outdeg,
    const float* __restrict__ b_conv, ushort* __restrict__ h2, int N)
{
    int n = (blockIdx.x * 256 + threadIdx.x) >> 6;
    int lane = threadIdx.x & 63;
    if (n >= N) return;
    const int g = lane >> 4;
    const int c = lane & 15;
    int e0 = rp[n], e1 = rp[n + 1];

    float a[8];
#pragma unroll
    for (int j = 0; j < 8; ++j) a[j] = 0.f;

    int e = e0 + g;
    for (; e + 4 < e1; e += 8) {           // 2 edges in flight per lane
        int s0 = src[e], s1 = src[e + 4];
        float sc0 = rsqrtf((float)max(outdeg[s0], 1));
        float sc1 = rsqrtf((float)max(outdeg[s1], 1));
        short8 v0 = *(const short8*)&h1[(size_t)s0 * 128 + c * 8];
        short8 v1 = *(const short8*)&h1[(size_t)s1 * 128 + c * 8];
#pragma unroll
        for (int j = 0; j < 8; ++j)
            a[j] = fmaf(sc0, bf2f((unsigned short)v0[j]),
                        fmaf(sc1, bf2f((unsigned short)v1[j]), a[j]));
    }
    if (e < e1) {
        int s0 = src[e];
        float sc0 = rsqrtf((float)max(outdeg[s0], 1));
        short8 v0 = *(const short8*)&h1[(size_t)s0 * 128 + c * 8];
#pragma unroll
        for (int j = 0; j < 8; ++j)
            a[j] = fmaf(sc0, bf2f((unsigned short)v0[j]), a[j]);
    }

#pragma unroll
    for (int j = 0; j < 8; ++j) {
        a[j] += __shfl_xor(a[j], 16, 64);
        a[j] += __shfl_xor(a[j], 32, 64);
    }

    if (g == 0) {
        float sc = rsqrtf((float)max(e1 - e0, 1));
        ushort o[8];
#pragma unroll
        for (int j = 0; j < 8; ++j)
            o[j] = f2bf(fmaxf(fmaf(a[j], sc, b_conv[c * 8 + j]), 0.f));
        *(short8*)&h2[(size_t)n * 128 + c * 8] = *(const short8*)o;
    }
}

// ---------------------------------------------------------------------------
// Fused GEMM2+GEMM3: per 64-row block,
//   stage1: T = relu(h2 @ W1^T + b1)        [64 x 128] -> bf16 in LDS (Ts)
//   stage2: out = T @ W2^T + b2             [64 x 256] -> f32 global
// LDS: stage1 As[8K]+Bs[16K]; Ts aliases [0,16K); Bs2 at [16K,48K).
__global__ __launch_bounds__(256) void gemm23_kernel(
    const ushort* __restrict__ A, const ushort* __restrict__ W1b,
    const ushort* __restrict__ W2b, const float* __restrict__ b1,
    const float* __restrict__ b2, float* __restrict__ out, int nRows)
{
    __shared__ char lds_raw[49152];
    ushort* As  = (ushort*)lds_raw;             // [64][64]   stage1
    ushort* Bs  = (ushort*)(lds_raw + 8192);    // [128][64]  stage1
    ushort* Ts  = (ushort*)lds_raw;             // [64][128]  stage2 A
    ushort* Bs2 = (ushort*)(lds_raw + 16384);   // [256][64]  stage2 B

    const int tid  = threadIdx.x;
    const int lane = tid & 63;
    const int w    = tid >> 6;
    const int r    = lane & 15;
    const int q    = lane >> 4;
    const int row0 = blockIdx.x * 64;

    // ---------------- stage 1: h2 @ W1^T ----------------
    f32x4 acc1[8];
#pragma unroll
    for (int t = 0; t < 8; ++t) acc1[t] = (f32x4){0.f, 0.f, 0.f, 0.f};

    for (int k0 = 0; k0 < 128; k0 += 64) {
        __syncthreads();
#pragma unroll
        for (int s = 0; s < 2; ++s) {
            int idx = s * 256 + tid;
            int row = idx >> 3, kg = idx & 7;
            int g = row0 + row;
            short8 v = (short8){0, 0, 0, 0, 0, 0, 0, 0};
            if (g < nRows)
                v = *(const short8*)&A[(size_t)g * 128 + k0 + kg * 8];
            *(short8*)&As[row * 64 + ((kg ^ (row & 7)) * 8)] = v;
        }
#pragma unroll
        for (int s = 0; s < 4; ++s) {
            int idx = s * 256 + tid;
            int col = idx >> 3, kg = idx & 7;
            *(short8*)&Bs[col * 64 + ((kg ^ (col & 7)) * 8)] =
                *(const short8*)&W1b[(size_t)col * 128 + k0 + kg * 8];
        }
        __syncthreads();

#pragma unroll
        for (int ks = 0; ks < 2; ++ks) {
            short8 af = *(const short8*)&As[(w * 16 + r) * 64 + (((ks * 4 + q) ^ (r & 7)) * 8)];
#pragma unroll
            for (int t = 0; t < 8; ++t) {
                short8 bf = *(const short8*)&Bs[(t * 16 + r) * 64 + (((ks * 4 + q) ^ (r & 7)) * 8)];
                acc1[t] = __builtin_amdgcn_mfma_f32_16x16x32_bf16(af, bf, acc1[t], 0, 0, 0);
            }
        }
    }

    // T = relu(acc1 + b1) -> Ts (bf16, swizzled [64][128])
    __syncthreads();
#pragma unroll
    for (int t = 0; t < 8; ++t) {
        int col = t * 16 + r;
        float bo = b1[col];
        int slot = col >> 3;
#pragma unroll
        for (int reg = 0; reg < 4; ++reg) {
            int row = w * 16 + q * 4 + reg;
            float v = fmaxf(acc1[t][reg] + bo, 0.f);
            Ts[row * 128 + ((slot ^ (row & 7)) << 3) + (col & 7)] = f2bf(v);
        }
    }

    // ---------------- stage 2: T @ W2^T ----------------
    f32x4 acc2[16];
#pragma unroll
    for (int t = 0; t < 16; ++t) acc2[t] = (f32x4){0.f, 0.f, 0.f, 0.f};

    for (int k0 = 0; k0 < 128; k0 += 64) {
        __syncthreads();
#pragma unroll
        for (int s = 0; s < 8; ++s) {
            int idx = s * 256 + tid;         // 0..2047
            int col = idx >> 3, kg = idx & 7;
            *(short8*)&Bs2[col * 64 + ((kg ^ (col & 7)) * 8)] =
                *(const short8*)&W2b[(size_t)col * 128 + k0 + kg * 8];
        }
        __syncthreads();

#pragma unroll
        for (int ks = 0; ks < 2; ++ks) {
            int slot = (k0 >> 3) + ks * 4 + q;       // 0..15 within Ts row
            short8 af = *(const short8*)&Ts[(w * 16 + r) * 128 + ((slot ^ (r & 7)) * 8)];
#pragma unroll
            for (int t = 0; t < 16; ++t) {
                short8 bf = *(const short8*)&Bs2[(t * 16 + r) * 64 + (((ks * 4 + q) ^ (r & 7)) * 8)];
                acc2[t] = __builtin_amdgcn_mfma_f32_16x16x32_bf16(af, bf, acc2[t], 0, 0, 0);
            }
        }
    }

    // epilogue: f32 out + b2
#pragma unroll
    for (int t = 0; t < 16; ++t) {
        int col = t * 16 + r;
        float bo = b2[col];
#pragma unroll
        for (int reg = 0; reg < 4; ++reg) {
            int g = row0 + w * 16 + q * 4 + reg;
            if (g < nRows)
                out[(size_t)g * 256 + col] = acc2[t][reg] + bo;
        }
    }
}

// ---------------------------------------------------------------------------
extern "C" void kernel_launch(void* const* d_in, const int* in_sizes, int n_in,
                              void* d_out, int out_size, void* d_ws, size_t ws_size,
                              hipStream_t stream)
{
    const float* x      = (const float*)d_in[0];
    const int*   src    = (const int*)d_in[1];
    const int*   dst    = (const int*)d_in[2];
    const float* W_conv = (const float*)d_in[3];
    const float* b_conv = (const float*)d_in[4];
    const float* W1     = (const float*)d_in[5];
    const float* b1     = (const float*)d_in[6];
    const float* W2     = (const float*)d_in[7];
    const float* b2     = (const float*)d_in[8];
    float* out = (float*)d_out;

    const int N  = in_sizes[0] / 256;   // 100000
    const int nE = in_sizes[1];         // 1600000

    // ws layout (ushort units unless noted):
    // h1 [N*128] | h2 [N*128] | WcT [128*256] | W1b [128*128] | W2b [256*128]
    // | outdeg [N int] | row_ptr [N+1 int]
    ushort* h1  = (ushort*)d_ws;
    ushort* h2  = h1 + (size_t)N * 128;
    ushort* WcT = h2 + (size_t)N * 128;
    ushort* W1b = WcT + 128 * 256;
    ushort* W2b = W1b + 128 * 128;
    int* outdeg = (int*)(W2b + 256 * 128);
    int* rp     = outdeg + N;

    hipMemsetAsync(outdeg, 0, (size_t)N * sizeof(int), stream);

    wprep_kernel<<<(128 * 256 + 128 * 128 + 256 * 128 + 255) / 256, 256, 0, stream>>>(
        W_conv, W1, W2, WcT, W1b, W2b);

    const int nBlocks = (N + 63) / 64;   // 1563; also covers 1563*1024 >= nE edges
    // h1 = bf16[x @ W_conv]  (+ fused outdeg histogram)
    gemm1_kernel<<<nBlocks, 256, 0, stream>>>(x, WcT, src, outdeg, h1, N, nE);

    rowptr_kernel<<<(nE + 255) / 256, 256, 0, stream>>>(dst, rp, nE, N);

    // h2 = bf16[relu( (sum_e rsqrt(outdeg[src])*h1[src]) * rsqrt(indeg) + b_conv )]
    gather_kernel<<<(N * 64 + 255) / 256, 256, 0, stream>>>(
        h1, src, rp, outdeg, b_conv, h2, N);

    // out = relu(h2 @ W1^T + b1) @ W2^T + b2   (single fused kernel)
    gemm23_kernel<<<nBlocks, 256, 0, stream>>>(h2, W1b, W2b, b1, b2, out, N);
}